// Round 11
// baseline (483.788 us; speedup 1.0000x reference)
//
#include <hip/hip_runtime.h>
#include <stdint.h>

#define Hdim 1024
#define Bdim 8
#define Sdim 2048
#define Edim 8
#define Mtot 16384
#define Ntot 8192   // n' = d*8 + e

typedef short bf16x8 __attribute__((ext_vector_type(8)));
typedef unsigned short u16x8 __attribute__((ext_vector_type(8)));
typedef float f32x4 __attribute__((ext_vector_type(4)));

__device__ __forceinline__ unsigned short f2bf(float f) {
  union { float f; unsigned u; } v; v.f = f;
  unsigned r = (v.u + 0x7FFFu + ((v.u >> 16) & 1u)) >> 16;
  return (unsigned short)r;
}

__device__ __forceinline__ void gload16(const void* g, void* l) {
  __builtin_amdgcn_global_load_lds((const __attribute__((address_space(1))) void*)g,
                                   (__attribute__((address_space(3))) void*)l,
                                   16, 0, 0);
}

// ---------------- kernel 1: fused {convert+mean-partials} / {W transpose} ----------
__global__ void k_prep(const float* __restrict__ x,
                       unsigned short* __restrict__ xb,
                       float* __restrict__ part,
                       const float* __restrict__ We,
                       unsigned short* __restrict__ wt) {
  __shared__ float tl[64][65];
  const int bid = blockIdx.x;
  const int t = threadIdx.x;
  if (bid < 512) {
    const int b = bid >> 6;
    const int s0 = (bid & 63) * 32;
    const int hg = (t & 127) << 3;
    const int sp = t >> 7;
    float accv[8];
#pragma unroll
    for (int q = 0; q < 8; ++q) accv[q] = 0.f;
#pragma unroll 4
    for (int i = 0; i < 16; ++i) {
      const int s = s0 + sp + (i << 1);
      const size_t base = ((size_t)b * Sdim + s) * Hdim + hg;
      const float4 lo = *(const float4*)(x + base);
      const float4 hi = *(const float4*)(x + base + 4);
      accv[0] += lo.x; accv[1] += lo.y; accv[2] += lo.z; accv[3] += lo.w;
      accv[4] += hi.x; accv[5] += hi.y; accv[6] += hi.z; accv[7] += hi.w;
      u16x8 pk;
      pk[0] = f2bf(lo.x); pk[1] = f2bf(lo.y); pk[2] = f2bf(lo.z); pk[3] = f2bf(lo.w);
      pk[4] = f2bf(hi.x); pk[5] = f2bf(hi.y); pk[6] = f2bf(hi.z); pk[7] = f2bf(hi.w);
      *(u16x8*)(xb + base) = pk;
    }
    float* pp = part + ((size_t)b * 128 + (bid & 63) * 2 + sp) * Hdim + hg;
#pragma unroll
    for (int q = 0; q < 8; ++q) pp[q] = accv[q];
  } else {
    const int tb = bid - 512;
    const int e = tb >> 8, hb = (tb >> 4) & 15, db = tb & 15;
    const float* src = We + ((size_t)e * Hdim + hb * 64) * Hdim + db * 64;
#pragma unroll
    for (int it = 0; it < 4; ++it) {
      int idx = it * 256 + t;
      int r = idx >> 4, c4 = (idx & 15) << 2;
      const float4 v = *(const float4*)(src + (size_t)r * Hdim + c4);
      tl[r][c4] = v.x; tl[r][c4 + 1] = v.y; tl[r][c4 + 2] = v.z; tl[r][c4 + 3] = v.w;
    }
    __syncthreads();
#pragma unroll
    for (int it = 0; it < 2; ++it) {
      int idx = it * 256 + t;
      int rr = idx >> 3, cg = (idx & 7) << 3;
      u16x8 pk;
#pragma unroll
      for (int q = 0; q < 8; ++q) pk[q] = f2bf(tl[cg + q][rr]);
      const int np = (db * 64 + rr) * 8 + e;
      *(u16x8*)(wt + (size_t)np * Hdim + hb * 64 + cg) = pk;
    }
  }
}

// ---------------- kernel 2: fused router (mean finish + MLP + softmax), 8 blocks ---
__global__ void k_router(const float* __restrict__ part,
                         const float* __restrict__ Wr1,
                         const float* __restrict__ br1,
                         const float* __restrict__ Wr2,
                         const float* __restrict__ br2,
                         float* __restrict__ routing) {
  __shared__ float xs[Hdim];
  __shared__ float hs[Hdim];
  __shared__ float red[64];
  const int b = blockIdx.x, t = threadIdx.x;
  for (int h = t; h < Hdim; h += 256) {
    float s = 0.f;
    const float* p = part + (size_t)b * 128 * Hdim + h;
#pragma unroll 8
    for (int c = 0; c < 128; ++c) s += p[(size_t)c * Hdim];
    xs[h] = s * (1.0f / 2048.0f);
  }
  __syncthreads();
  float a0 = 0.f, a1 = 0.f, a2 = 0.f, a3 = 0.f;
#pragma unroll 4
  for (int k = 0; k < Hdim; ++k) {
    const float xv = xs[k];
    const float* w = Wr1 + (size_t)k * Hdim + t;
    a0 = fmaf(xv, w[0],   a0);
    a1 = fmaf(xv, w[256], a1);
    a2 = fmaf(xv, w[512], a2);
    a3 = fmaf(xv, w[768], a3);
  }
  hs[t]       = fmaxf(a0 + br1[t],       0.f);
  hs[t + 256] = fmaxf(a1 + br1[t + 256], 0.f);
  hs[t + 512] = fmaxf(a2 + br1[t + 512], 0.f);
  hs[t + 768] = fmaxf(a3 + br1[t + 768], 0.f);
  __syncthreads();
  if (t < 64) {
    const int e = t & 7;
    const int kb = (t >> 3) * 128;
    float s = 0.f;
#pragma unroll 8
    for (int k = kb; k < kb + 128; ++k) s = fmaf(hs[k], Wr2[k * Edim + e], s);
    red[t] = s;
  }
  __syncthreads();
  if (t < 8) {
    float l = br2[t];
#pragma unroll
    for (int q = 0; q < 8; ++q) l += red[q * 8 + t];
    red[t] = l;
  }
  __syncthreads();
  if (t == 0) {
    float m = red[0];
#pragma unroll
    for (int e = 1; e < 8; ++e) m = fmaxf(m, red[e]);
    float p[8]; float s = 0.f;
#pragma unroll
    for (int e = 0; e < 8; ++e) { p[e] = __expf(red[e] - m); s += p[e]; }
#pragma unroll
    for (int e = 0; e < 8; ++e) routing[b * Edim + e] = p[e] / s;
  }
}

// ---------------- kernel 3: m97-structure 128x128 fused GEMM (R8, 5 blocks/CU) -----
// 4 waves (2x2, 64x64 each), BK=64, single-buffer EXACTLY 32KB LDS -> 5 blocks/CU.
// Plain __syncthreads() loop (compiler-managed waitcnts), 16B global_load_lds,
// XOR-swizzled LDS. Cross-block TLP (20 waves/CU) provides DS|MFMA overlap.
__global__ __launch_bounds__(256, 5)
void k_moe_gemm(const unsigned short* __restrict__ xb,
                const unsigned short* __restrict__ wt,
                const float* __restrict__ be,
                const float* __restrict__ routing,
                float* __restrict__ out) {
  __shared__ char smem[32768];   // As [128][64] @0, Bs [128][64] @16384; epilogue reuse
  const int t = threadIdx.x;
  const int wave = t >> 6, lane = t & 63;
  const int la15 = lane & 15;
  const int wr = wave >> 1, wc = wave & 1;

  // L2-banded bijective mapping: xcd = bid&7 owns 16 m-tiles (= batch xcd)
  const int bid = blockIdx.x;
  const int xcd = bid & 7;
  const int i = bid >> 3;             // 0..1023
  const int m0 = (xcd * 16 + (i & 15)) * 128;
  const int n0 = (i >> 4) * 128;

  // staging: thread covers row (chunk*8 + lane>>3), phys 16B-chunk lane&7,
  // global logical chunk = (lane&7) ^ (lane>>3)  (pre-swizzled source)
  const int cx = (((lane & 7) ^ (lane >> 3)) << 3);
  const unsigned short* aStage = xb + (size_t)(m0 + (lane >> 3)) * Hdim + cx;
  const unsigned short* bStage = wt + (size_t)(n0 + (lane >> 3)) * Hdim + cx;

  // fragment reads: row&7 == lane&7; phys chunk = logical ^ (row&7)
  const int aOff = (wr * 64 + la15) * 128;
  const int bOff = (wc * 64 + la15) * 128;
  const int swz0 = (((lane >> 4) ^ (lane & 7)) << 4);
  const int swz1 = (((4 + (lane >> 4)) ^ (lane & 7)) << 4);

  f32x4 acc[4][4];
#pragma unroll
  for (int ii = 0; ii < 4; ++ii)
#pragma unroll
    for (int jj = 0; jj < 4; ++jj) acc[ii][jj] = (f32x4){0.f, 0.f, 0.f, 0.f};

  for (int k0 = 0; k0 < Hdim; k0 += 64) {
    __syncthreads();   // all reads of previous tile done
#pragma unroll
    for (int p = 0; p < 4; ++p) {
      const int c = p * 4 + wave;
      gload16(aStage + (size_t)c * 8 * Hdim + k0, smem + c * 1024);
    }
#pragma unroll
    for (int p = 0; p < 4; ++p) {
      const int c = p * 4 + wave;
      gload16(bStage + (size_t)c * 8 * Hdim + k0, smem + 16384 + c * 1024);
    }
    __syncthreads();   // compiler drains vmcnt before barrier -> LDS ready
    {
      bf16x8 af[4], bf[4];
#pragma unroll
      for (int ii = 0; ii < 4; ++ii)
        af[ii] = *(const bf16x8*)(smem + aOff + ii * 2048 + swz0);
#pragma unroll
      for (int jj = 0; jj < 4; ++jj)
        bf[jj] = *(const bf16x8*)(smem + 16384 + bOff + jj * 2048 + swz0);
#pragma unroll
      for (int ii = 0; ii < 4; ++ii)
#pragma unroll
        for (int jj = 0; jj < 4; ++jj)
          acc[ii][jj] = __builtin_amdgcn_mfma_f32_16x16x32_bf16(af[ii], bf[jj], acc[ii][jj], 0, 0, 0);
#pragma unroll
      for (int ii = 0; ii < 4; ++ii)
        af[ii] = *(const bf16x8*)(smem + aOff + ii * 2048 + swz1);
#pragma unroll
      for (int jj = 0; jj < 4; ++jj)
        bf[jj] = *(const bf16x8*)(smem + 16384 + bOff + jj * 2048 + swz1);
#pragma unroll
      for (int ii = 0; ii < 4; ++ii)
#pragma unroll
        for (int jj = 0; jj < 4; ++jj)
          acc[ii][jj] = __builtin_amdgcn_mfma_f32_16x16x32_bf16(af[ii], bf[jj], acc[ii][jj], 0, 0, 0);
    }
  }
  __syncthreads();   // all LDS reads done -> safe to reuse as out staging

  // ---------------- epilogue: bias + relu + routing weight + e-reduce ----------------
  float* outb = (float*)smem;                 // [128][17] padded f32
  const int bidx = m0 >> 11;                  // == xcd
  const float rw = routing[bidx * Edim + (lane & 7)];
  const bool writer = ((lane & 7) == 0);
#pragma unroll
  for (int j = 0; j < 4; ++j) {
    const int dloc = wc * 8 + j * 2 + ((lane >> 3) & 1);
    const float bias = be[(lane & 7) * Hdim + (n0 >> 3) + dloc];
#pragma unroll
    for (int ii = 0; ii < 4; ++ii) {
#pragma unroll
      for (int r = 0; r < 4; ++r) {
        float v = fmaxf(acc[ii][j][r] + bias, 0.f) * rw;
        v += __shfl_xor(v, 1, 64);
        v += __shfl_xor(v, 2, 64);
        v += __shfl_xor(v, 4, 64);
        if (writer) {
          const int row = wr * 64 + ii * 16 + ((lane >> 4) << 2) + r;
          outb[row * 17 + dloc] = v;
        }
      }
    }
  }
  __syncthreads();
  // coalesced store of the block's 128 x 16 f32 out-tile
  const size_t obase = (size_t)m0 * Hdim + (n0 >> 3);
#pragma unroll
  for (int it = 0; it < 2; ++it) {
    const int idx = it * 256 + t;
    const int r = idx >> 2;
    const int c = (idx & 3) << 2;
    float4 vv;
    vv.x = outb[r * 17 + c];
    vv.y = outb[r * 17 + c + 1];
    vv.z = outb[r * 17 + c + 2];
    vv.w = outb[r * 17 + c + 3];
    *(float4*)(out + obase + (size_t)r * Hdim + c) = vv;
  }
}

extern "C" void kernel_launch(void* const* d_in, const int* in_sizes, int n_in,
                              void* d_out, int out_size, void* d_ws, size_t ws_size,
                              hipStream_t stream) {
  const float* x   = (const float*)d_in[0];
  const float* We  = (const float*)d_in[1];
  const float* be  = (const float*)d_in[2];
  const float* Wr1 = (const float*)d_in[3];
  const float* br1 = (const float*)d_in[4];
  const float* Wr2 = (const float*)d_in[5];
  const float* br2 = (const float*)d_in[6];
  float* out = (float*)d_out;

  char* ws = (char*)d_ws;
  unsigned short* xb = (unsigned short*)ws;                  // 33,554,432 B
  unsigned short* wt = (unsigned short*)(ws + 33554432);     // 16,777,216 B
  float* part    = (float*)(ws + 50331648);                  //  4,194,304 B
  float* routing = (float*)(ws + 54525952);                  //        256 B

  k_prep<<<dim3(2560), 256, 0, stream>>>(x, xb, part, We, wt);
  k_router<<<dim3(Bdim), 256, 0, stream>>>(part, Wr1, br1, Wr2, br2, routing);
  k_moe_gemm<<<dim3(8192), 256, 0, stream>>>(xb, wt, be, routing, out);
}

// Round 12
// 418.216 us; speedup vs baseline: 1.1568x; 1.1568x over previous
//
#include <hip/hip_runtime.h>
#include <stdint.h>

#define Hdim 1024
#define Bdim 8
#define Sdim 2048
#define Edim 8
#define Mtot 16384
#define Ntot 8192   // n' = d*8 + e

typedef short bf16x8 __attribute__((ext_vector_type(8)));
typedef unsigned short u16x8 __attribute__((ext_vector_type(8)));
typedef float f32x4 __attribute__((ext_vector_type(4)));

__device__ __forceinline__ unsigned short f2bf(float f) {
  union { float f; unsigned u; } v; v.f = f;
  unsigned r = (v.u + 0x7FFFu + ((v.u >> 16) & 1u)) >> 16;
  return (unsigned short)r;
}

__device__ __forceinline__ void gload16(const void* g, void* l) {
  __builtin_amdgcn_global_load_lds((const __attribute__((address_space(1))) void*)g,
                                   (__attribute__((address_space(3))) void*)l,
                                   16, 0, 0);
}

#define VMCNT_(N) asm volatile("s_waitcnt vmcnt(" #N ")" ::: "memory")
#define VMCNT(N) VMCNT_(N)
#define BAR() __builtin_amdgcn_s_barrier()

// ---------------- kernel 1: fused {convert+mean-partials} / {W transpose} ----------
__global__ void k_prep(const float* __restrict__ x,
                       unsigned short* __restrict__ xb,
                       float* __restrict__ part,
                       const float* __restrict__ We,
                       unsigned short* __restrict__ wt) {
  __shared__ float tl[64][65];
  const int bid = blockIdx.x;
  const int t = threadIdx.x;
  if (bid < 512) {
    const int b = bid >> 6;
    const int s0 = (bid & 63) * 32;
    const int hg = (t & 127) << 3;
    const int sp = t >> 7;
    float accv[8];
#pragma unroll
    for (int q = 0; q < 8; ++q) accv[q] = 0.f;
#pragma unroll 4
    for (int i = 0; i < 16; ++i) {
      const int s = s0 + sp + (i << 1);
      const size_t base = ((size_t)b * Sdim + s) * Hdim + hg;
      const float4 lo = *(const float4*)(x + base);
      const float4 hi = *(const float4*)(x + base + 4);
      accv[0] += lo.x; accv[1] += lo.y; accv[2] += lo.z; accv[3] += lo.w;
      accv[4] += hi.x; accv[5] += hi.y; accv[6] += hi.z; accv[7] += hi.w;
      u16x8 pk;
      pk[0] = f2bf(lo.x); pk[1] = f2bf(lo.y); pk[2] = f2bf(lo.z); pk[3] = f2bf(lo.w);
      pk[4] = f2bf(hi.x); pk[5] = f2bf(hi.y); pk[6] = f2bf(hi.z); pk[7] = f2bf(hi.w);
      *(u16x8*)(xb + base) = pk;
    }
    float* pp = part + ((size_t)b * 128 + (bid & 63) * 2 + sp) * Hdim + hg;
#pragma unroll
    for (int q = 0; q < 8; ++q) pp[q] = accv[q];
  } else {
    const int tb = bid - 512;
    const int e = tb >> 8, hb = (tb >> 4) & 15, db = tb & 15;
    const float* src = We + ((size_t)e * Hdim + hb * 64) * Hdim + db * 64;
#pragma unroll
    for (int it = 0; it < 4; ++it) {
      int idx = it * 256 + t;
      int r = idx >> 4, c4 = (idx & 15) << 2;
      const float4 v = *(const float4*)(src + (size_t)r * Hdim + c4);
      tl[r][c4] = v.x; tl[r][c4 + 1] = v.y; tl[r][c4 + 2] = v.z; tl[r][c4 + 3] = v.w;
    }
    __syncthreads();
#pragma unroll
    for (int it = 0; it < 2; ++it) {
      int idx = it * 256 + t;
      int rr = idx >> 3, cg = (idx & 7) << 3;
      u16x8 pk;
#pragma unroll
      for (int q = 0; q < 8; ++q) pk[q] = f2bf(tl[cg + q][rr]);
      const int np = (db * 64 + rr) * 8 + e;
      *(u16x8*)(wt + (size_t)np * Hdim + hb * 64 + cg) = pk;
    }
  }
}

// ---------------- kernel 2: finish mean -> xm [B][H] ------------------------------
__global__ void k_mean(const float* __restrict__ part, float* __restrict__ xm) {
  __shared__ float red[4][64];
  const int b = blockIdx.y, hc = blockIdx.x, t = threadIdx.x;
  const int h = hc * 64 + (t & 63), q = t >> 6;
  float s = 0.f;
  const float* p = part + ((size_t)b * 128 + q * 32) * Hdim + h;
#pragma unroll 8
  for (int c = 0; c < 32; ++c) s += p[(size_t)c * Hdim];
  red[q][t & 63] = s;
  __syncthreads();
  if (t < 64) {
    float v = (red[0][t] + red[1][t]) + (red[2][t] + red[3][t]);
    xm[b * Hdim + hc * 64 + t] = v * (1.0f / 2048.0f);
  }
}

// ---------------- kernel 3: h = relu(xm @ Wr1 + br1) ------------------------------
__global__ void k_r1(const float* __restrict__ xm,
                     const float* __restrict__ Wr1,
                     const float* __restrict__ br1,
                     float* __restrict__ hbuf) {
  __shared__ float xs[Hdim];
  __shared__ float hred[2][128];
  const int b = blockIdx.y, jc = blockIdx.x, t = threadIdx.x;
  for (int k = t; k < Hdim; k += 256) xs[k] = xm[b * Hdim + k];
  __syncthreads();
  const int j = jc * 128 + (t & 127);
  const int kh = (t >> 7) * 512;
  float acc = 0.f;
#pragma unroll 8
  for (int k = 0; k < 512; ++k)
    acc = fmaf(xs[kh + k], Wr1[(size_t)(kh + k) * Hdim + j], acc);
  hred[t >> 7][t & 127] = acc;
  __syncthreads();
  if (t < 128)
    hbuf[b * Hdim + jc * 128 + t] =
        fmaxf(hred[0][t] + hred[1][t] + br1[jc * 128 + t], 0.f);
}

// ---------------- kernel 4: logits + softmax -> routing [B][E] ---------------------
__global__ void k_router2(const float* __restrict__ hbuf,
                          const float* __restrict__ Wr2,
                          const float* __restrict__ br2,
                          float* __restrict__ routing) {
  const int t = threadIdx.x;
  const int e = t & 7;
  const int b = t >> 3;
  float acc = br2[e];
  const float* hb = hbuf + b * Hdim;
#pragma unroll 8
  for (int k = 0; k < Hdim; ++k) acc = fmaf(hb[k], Wr2[k * Edim + e], acc);
  float m = acc;
  for (int d = 1; d < 8; d <<= 1) m = fmaxf(m, __shfl_xor(m, d, 64));
  float p = __expf(acc - m);
  float s = p;
  for (int d = 1; d < 8; d <<= 1) s += __shfl_xor(s, d, 64);
  routing[t] = p / s;
}

// ---------------- kernel 5: 8-phase 256x256 GEMM, latency-safe vmcnt ---------------
// 8 waves (2M x 4N), per-wave 128x64. 2 K-tiles/iter (BK=64), 8 phases.
// Phase: {LD ops for this phase's MFMA; stage 1 unit; [p3/p7: VMCNT(6)]; BAR;
//         MFMA(setprio); BAR}.
// vmcnt(6) ONLY at p3/p7 ends: waits reach loads issued >=4 phases earlier
// (>=4 phase-times in flight >> HBM latency) -> never blocks. Every LD's unit
// is drained by a vmcnt+BAR strictly preceding it (FIFO-traced); WAR gaps >=1
// barrier; stage->read distance >= 6 phases.
__global__ __launch_bounds__(512, 2)
void k_moe_gemm(const unsigned short* __restrict__ xb,
                const unsigned short* __restrict__ wt,
                const float* __restrict__ be,
                const float* __restrict__ routing,
                float* __restrict__ out) {
  extern __shared__ char smem[];
  const int t = threadIdx.x;
  const int wave = t >> 6, lane = t & 63;
  const int la15 = lane & 15;
  const int wr = wave >> 2;    // 0..1
  const int wcn = wave & 3;    // 0..3

  // L2-blocked bijective mapping (XCD x owns one 8-m-tile band)
  const int bid = blockIdx.x;
  const int xcd = bid & 7;
  const int idx = bid >> 3;
  const int rnd = idx >> 5;
  const int slot = idx & 31;
  const int m0 = (xcd * 8 + (slot & 7)) * 256;
  const int n0 = (rnd * 4 + (slot >> 3)) * 256;

  const int cx = (((lane & 7) ^ (lane >> 3)) << 3);
  const unsigned short* aStage = xb + (size_t)(m0 + wave * 8 + (lane >> 3)) * Hdim + cx;
  const int bRowLoc = ((wave & 3) << 3) + ((wave >> 2) << 6) + (lane >> 3);
  const unsigned short* bStage = wt + (size_t)(n0 + bRowLoc) * Hdim + cx;
  const int aLdsW = wave * 1024;
  const int bLdsW = ((wave & 3) << 10) + ((wave >> 2) << 13);

  const int swz0 = (((lane >> 4) ^ (lane & 7)) << 4);
  const int swz1 = ((((lane >> 4) + 4) ^ (lane & 7)) << 4);
  const int aRd = (wr * 128 + la15) * 128;
  const int bRd = (wcn * 64 + la15) * 128;

  f32x4 acc[8][4];
#pragma unroll
  for (int i = 0; i < 8; ++i)
#pragma unroll
    for (int j = 0; j < 4; ++j) acc[i][j] = (f32x4){0.f, 0.f, 0.f, 0.f};

  bf16x8 aLo[4][2], aHi[4][2], bLo[2][2], bHi[2][2];

#define STG_A(half, buf, k0) do { \
    gload16(aStage + (half) * 64 * 1024 + (k0),          smem + (buf) * 32768 + aLdsW + (half) * 8192); \
    gload16(aStage + (128 + (half) * 64) * 1024 + (k0),  smem + (buf) * 32768 + aLdsW + 16384 + (half) * 8192); \
  } while (0)
#define STG_B(sub, buf, k0) do { \
    gload16(bStage + (sub) * 32 * 1024 + (k0),           smem + 65536 + (buf) * 32768 + bLdsW + (sub) * 4096); \
    gload16(bStage + (128 + (sub) * 32) * 1024 + (k0),   smem + 65536 + (buf) * 32768 + bLdsW + 16384 + (sub) * 4096); \
  } while (0)
#define LD_A(dst, buf, qi) do { \
    _Pragma("unroll") for (int ii = 0; ii < 4; ++ii) { \
      dst[ii][0] = *(const bf16x8*)(smem + (buf) * 32768 + aRd + (qi) * 8192 + ii * 2048 + swz0); \
      dst[ii][1] = *(const bf16x8*)(smem + (buf) * 32768 + aRd + (qi) * 8192 + ii * 2048 + swz1); } \
  } while (0)
#define LD_B(dst, buf, qj) do { \
    _Pragma("unroll") for (int jj = 0; jj < 2; ++jj) { \
      dst[jj][0] = *(const bf16x8*)(smem + 65536 + (buf) * 32768 + bRd + (qj) * 4096 + jj * 2048 + swz0); \
      dst[jj][1] = *(const bf16x8*)(smem + 65536 + (buf) * 32768 + bRd + (qj) * 4096 + jj * 2048 + swz1); } \
  } while (0)
#define MF_Q(af_, bf_, qi, jh) do { \
    __builtin_amdgcn_s_setprio(1); \
    _Pragma("unroll") for (int ii = 0; ii < 4; ++ii) \
      _Pragma("unroll") for (int jj = 0; jj < 2; ++jj) { \
        acc[(qi)*4+ii][(jh)*2+jj] = __builtin_amdgcn_mfma_f32_16x16x32_bf16(af_[ii][0], bf_[jj][0], acc[(qi)*4+ii][(jh)*2+jj], 0, 0, 0); \
        acc[(qi)*4+ii][(jh)*2+jj] = __builtin_amdgcn_mfma_f32_16x16x32_bf16(af_[ii][1], bf_[jj][1], acc[(qi)*4+ii][(jh)*2+jj], 0, 0, 0); } \
    __builtin_amdgcn_s_setprio(0); \
  } while (0)

  // ---- prologue: 7 units (t0 all four + t1 {A.h0,B.h0,B.h1}); A.h1(t1) staged p0 ----
  STG_A(0, 0, 0);    // unit1 (loads 1-2)
  STG_B(0, 0, 0);    // unit2
  STG_B(1, 0, 0);    // unit3
  STG_A(1, 0, 0);    // unit4
  STG_A(0, 1, 64);   // unit5
  STG_B(0, 1, 64);   // unit6
  STG_B(1, 1, 64);   // unit7
  VMCNT(6);          // drains units 1-4 (t0 complete); 3 units in flight
  BAR();

#pragma unroll 1
  for (int j = 0; j < 8; ++j) {
    const int kOdd = j * 128 + 64;            // tile 2j+1 (buf1): A.h1 staged at p0
    const int k2 = (j * 128 + 128) & 1023;    // tile 2j+2 -> buf0
    const int k3 = (j * 128 + 192) & 1023;    // tile 2j+3 -> buf1
    // p0: LD aLo,bLo (buf0); stage A.h1(t2j+1 -> buf1)
    LD_A(aLo, 0, 0); LD_B(bLo, 0, 0); STG_A(1, 1, kOdd);
    BAR();
    MF_Q(aLo, bLo, 0, 0);
    BAR();
    // p1: LD bHi (buf0); stage A.h0(t2j+2 -> buf0)
    LD_B(bHi, 0, 1); STG_A(0, 0, k2);
    BAR();
    MF_Q(aLo, bHi, 0, 1);
    BAR();
    // p2: LD aHi (buf0); stage B.h0(t2j+2)
    LD_A(aHi, 0, 1); STG_B(0, 0, k2);
    BAR();
    MF_Q(aHi, bHi, 1, 1);
    BAR();
    // p3: no LD; stage B.h1(t2j+2); VMCNT(6) -> drains through p0's unit
    STG_B(1, 0, k2);
    VMCNT(6);
    BAR();
    MF_Q(aHi, bLo, 1, 0);
    BAR();
    // p4: LD aLo,bLo (buf1); stage A.h1(t2j+2)
    LD_A(aLo, 1, 0); LD_B(bLo, 1, 0); STG_A(1, 0, k2);
    BAR();
    MF_Q(aLo, bLo, 0, 0);
    BAR();
    // p5: LD bHi (buf1); stage A.h0(t2j+3 -> buf1)
    LD_B(bHi, 1, 1); STG_A(0, 1, k3);
    BAR();
    MF_Q(aLo, bHi, 0, 1);
    BAR();
    // p6: LD aHi (buf1); stage B.h0(t2j+3)
    LD_A(aHi, 1, 1); STG_B(0, 1, k3);
    BAR();
    MF_Q(aHi, bHi, 1, 1);
    BAR();
    // p7: no LD; stage B.h1(t2j+3); VMCNT(6) -> drains through p4's unit
    STG_B(1, 1, k3);
    VMCNT(6);
    BAR();
    MF_Q(aHi, bLo, 1, 0);
    BAR();
  }

  VMCNT(0);   // drain tail stages before LDS reuse
  BAR();

  // ---------------- epilogue: bias + relu + routing weight + e-reduce ----------------
  float* outb = (float*)smem;                 // [256][33] padded
  const int bidx = m0 >> 11;
  const float rw = routing[bidx * Edim + (lane & 7)];
  const int dblk = (lane >> 3) & 1;
  const bool writer = ((lane & 7) == 0);
#pragma unroll
  for (int j = 0; j < 4; ++j) {
    const int col0 = wcn * 64 + j * 16;
    const float bias = be[(lane & 7) * Hdim + (n0 >> 3) + (col0 >> 3) + dblk];
#pragma unroll
    for (int i = 0; i < 8; ++i) {
#pragma unroll
      for (int r = 0; r < 4; ++r) {
        float v = fmaxf(acc[i][j][r] + bias, 0.f) * rw;
        v += __shfl_xor(v, 1, 64);
        v += __shfl_xor(v, 2, 64);
        v += __shfl_xor(v, 4, 64);
        if (writer) {
          const int row = wr * 128 + i * 16 + ((lane >> 4) << 2) + r;
          outb[row * 33 + (col0 >> 3) + dblk] = v;
        }
      }
    }
  }
  BAR();
  const size_t obase = (size_t)m0 * Hdim + (n0 >> 3);
#pragma unroll
  for (int it = 0; it < 4; ++it) {
    const int r = it * 64 + (t >> 3);
    const int c = (t & 7) * 4;
    float4 vv;
    vv.x = outb[r * 33 + c];
    vv.y = outb[r * 33 + c + 1];
    vv.z = outb[r * 33 + c + 2];
    vv.w = outb[r * 33 + c + 3];
    *(float4*)(out + obase + (size_t)r * Hdim + c) = vv;
  }
#undef STG_A
#undef STG_B
#undef LD_A
#undef LD_B
#undef MF_Q
}

extern "C" void kernel_launch(void* const* d_in, const int* in_sizes, int n_in,
                              void* d_out, int out_size, void* d_ws, size_t ws_size,
                              hipStream_t stream) {
  const float* x   = (const float*)d_in[0];
  const float* We  = (const float*)d_in[1];
  const float* be  = (const float*)d_in[2];
  const float* Wr1 = (const float*)d_in[3];
  const float* br1 = (const float*)d_in[4];
  const float* Wr2 = (const float*)d_in[5];
  const float* br2 = (const float*)d_in[6];
  float* out = (float*)d_out;

  char* ws = (char*)d_ws;
  unsigned short* xb = (unsigned short*)ws;                  // 33,554,432 B
  unsigned short* wt = (unsigned short*)(ws + 33554432);     // 16,777,216 B
  float* part    = (float*)(ws + 50331648);                  //  4,194,304 B
  float* xm      = (float*)(ws + 54525952);                  //     32,768 B
  float* hbuf    = (float*)(ws + 54558720);                  //     32,768 B
  float* routing = (float*)(ws + 54591488);                  //        256 B

  hipFuncSetAttribute((const void*)k_moe_gemm,
                      hipFuncAttributeMaxDynamicSharedMemorySize, 131072);

  k_prep<<<dim3(2560), 256, 0, stream>>>(x, xb, part, We, wt);
  k_mean<<<dim3(16, Bdim), 256, 0, stream>>>(part, xm);
  k_r1<<<dim3(8, Bdim), 256, 0, stream>>>(xm, Wr1, br1, hbuf);
  k_router2<<<1, 64, 0, stream>>>(hbuf, Wr2, br2, routing);
  k_moe_gemm<<<dim3(2048), 512, 131072, stream>>>(xb, wt, be, routing, out);
}

// Round 13
// 397.023 us; speedup vs baseline: 1.2185x; 1.0534x over previous
//
#include <hip/hip_runtime.h>
#include <stdint.h>

#define Hdim 1024
#define Bdim 8
#define Sdim 2048
#define Edim 8
#define Mtot 16384
#define Ntot 8192   // n' = d*8 + e

typedef short bf16x8 __attribute__((ext_vector_type(8)));
typedef unsigned short u16x8 __attribute__((ext_vector_type(8)));
typedef float f32x4 __attribute__((ext_vector_type(4)));

__device__ __forceinline__ unsigned short f2bf(float f) {
  union { float f; unsigned u; } v; v.f = f;
  unsigned r = (v.u + 0x7FFFu + ((v.u >> 16) & 1u)) >> 16;
  return (unsigned short)r;
}

__device__ __forceinline__ void gload16(const void* g, void* l) {
  __builtin_amdgcn_global_load_lds((const __attribute__((address_space(1))) void*)g,
                                   (__attribute__((address_space(3))) void*)l,
                                   16, 0, 0);
}

// ---------------- kernel 1: fused {convert+mean-partials} / {W transpose} ----------
__global__ void k_prep(const float* __restrict__ x,
                       unsigned short* __restrict__ xb,
                       float* __restrict__ part,
                       const float* __restrict__ We,
                       unsigned short* __restrict__ wt) {
  __shared__ float tl[64][65];
  const int bid = blockIdx.x;
  const int t = threadIdx.x;
  if (bid < 512) {
    const int b = bid >> 6;
    const int s0 = (bid & 63) * 32;
    const int hg = (t & 127) << 3;
    const int sp = t >> 7;
    float accv[8];
#pragma unroll
    for (int q = 0; q < 8; ++q) accv[q] = 0.f;
#pragma unroll 4
    for (int i = 0; i < 16; ++i) {
      const int s = s0 + sp + (i << 1);
      const size_t base = ((size_t)b * Sdim + s) * Hdim + hg;
      const float4 lo = *(const float4*)(x + base);
      const float4 hi = *(const float4*)(x + base + 4);
      accv[0] += lo.x; accv[1] += lo.y; accv[2] += lo.z; accv[3] += lo.w;
      accv[4] += hi.x; accv[5] += hi.y; accv[6] += hi.z; accv[7] += hi.w;
      u16x8 pk;
      pk[0] = f2bf(lo.x); pk[1] = f2bf(lo.y); pk[2] = f2bf(lo.z); pk[3] = f2bf(lo.w);
      pk[4] = f2bf(hi.x); pk[5] = f2bf(hi.y); pk[6] = f2bf(hi.z); pk[7] = f2bf(hi.w);
      *(u16x8*)(xb + base) = pk;
    }
    float* pp = part + ((size_t)b * 128 + (bid & 63) * 2 + sp) * Hdim + hg;
#pragma unroll
    for (int q = 0; q < 8; ++q) pp[q] = accv[q];
  } else {
    const int tb = bid - 512;
    const int e = tb >> 8, hb = (tb >> 4) & 15, db = tb & 15;
    const float* src = We + ((size_t)e * Hdim + hb * 64) * Hdim + db * 64;
#pragma unroll
    for (int it = 0; it < 4; ++it) {
      int idx = it * 256 + t;
      int r = idx >> 4, c4 = (idx & 15) << 2;
      const float4 v = *(const float4*)(src + (size_t)r * Hdim + c4);
      tl[r][c4] = v.x; tl[r][c4 + 1] = v.y; tl[r][c4 + 2] = v.z; tl[r][c4 + 3] = v.w;
    }
    __syncthreads();
#pragma unroll
    for (int it = 0; it < 2; ++it) {
      int idx = it * 256 + t;
      int rr = idx >> 3, cg = (idx & 7) << 3;
      u16x8 pk;
#pragma unroll
      for (int q = 0; q < 8; ++q) pk[q] = f2bf(tl[cg + q][rr]);
      const int np = (db * 64 + rr) * 8 + e;
      *(u16x8*)(wt + (size_t)np * Hdim + hb * 64 + cg) = pk;
    }
  }
}

// ---------------- kernel 2: finish mean -> xm [B][H] ------------------------------
__global__ void k_mean(const float* __restrict__ part, float* __restrict__ xm) {
  __shared__ float red[4][64];
  const int b = blockIdx.y, hc = blockIdx.x, t = threadIdx.x;
  const int h = hc * 64 + (t & 63), q = t >> 6;
  float s = 0.f;
  const float* p = part + ((size_t)b * 128 + q * 32) * Hdim + h;
#pragma unroll 8
  for (int c = 0; c < 32; ++c) s += p[(size_t)c * Hdim];
  red[q][t & 63] = s;
  __syncthreads();
  if (t < 64) {
    float v = (red[0][t] + red[1][t]) + (red[2][t] + red[3][t]);
    xm[b * Hdim + hc * 64 + t] = v * (1.0f / 2048.0f);
  }
}

// ---------------- kernel 3: h = relu(xm @ Wr1 + br1) ------------------------------
__global__ void k_r1(const float* __restrict__ xm,
                     const float* __restrict__ Wr1,
                     const float* __restrict__ br1,
                     float* __restrict__ hbuf) {
  __shared__ float xs[Hdim];
  __shared__ float hred[2][128];
  const int b = blockIdx.y, jc = blockIdx.x, t = threadIdx.x;
  for (int k = t; k < Hdim; k += 256) xs[k] = xm[b * Hdim + k];
  __syncthreads();
  const int j = jc * 128 + (t & 127);
  const int kh = (t >> 7) * 512;
  float acc = 0.f;
#pragma unroll 8
  for (int k = 0; k < 512; ++k)
    acc = fmaf(xs[kh + k], Wr1[(size_t)(kh + k) * Hdim + j], acc);
  hred[t >> 7][t & 127] = acc;
  __syncthreads();
  if (t < 128)
    hbuf[b * Hdim + jc * 128 + t] =
        fmaxf(hred[0][t] + hred[1][t] + br1[jc * 128 + t], 0.f);
}

// ---------------- kernel 4: logits + softmax -> routing [B][E] ---------------------
__global__ void k_router2(const float* __restrict__ hbuf,
                          const float* __restrict__ Wr2,
                          const float* __restrict__ br2,
                          float* __restrict__ routing) {
  const int t = threadIdx.x;
  const int e = t & 7;
  const int b = t >> 3;
  float acc = br2[e];
  const float* hb = hbuf + b * Hdim;
#pragma unroll 8
  for (int k = 0; k < Hdim; ++k) acc = fmaf(hb[k], Wr2[k * Edim + e], acc);
  float m = acc;
  for (int d = 1; d < 8; d <<= 1) m = fmaxf(m, __shfl_xor(m, d, 64));
  float p = __expf(acc - m);
  float s = p;
  for (int d = 1; d < 8; d <<= 1) s += __shfl_xor(s, d, 64);
  routing[t] = p / s;
}

// ---------------- kernel 5: m97-structure 128x128 fused GEMM (R8 best-of-session) --
// 4 waves (2x2, 64x64 each), BK=64, single-buffer EXACTLY 32KB LDS.
// Plain __syncthreads() loop (compiler-managed waitcnts), 16B global_load_lds,
// XOR-swizzled LDS. Cross-block TLP (4+ blocks/CU) provides DS|MFMA overlap.
// __launch_bounds__(256,4): min 4 blocks/CU for regalloc (VGPR 56); 5th block
// possible opportunistically with exact 32KB LDS.
__global__ __launch_bounds__(256, 4)
void k_moe_gemm(const unsigned short* __restrict__ xb,
                const unsigned short* __restrict__ wt,
                const float* __restrict__ be,
                const float* __restrict__ routing,
                float* __restrict__ out) {
  __shared__ char smem[32768];   // As [128][64] @0, Bs [128][64] @16384; epilogue reuse
  const int t = threadIdx.x;
  const int wave = t >> 6, lane = t & 63;
  const int la15 = lane & 15;
  const int wr = wave >> 1, wc = wave & 1;

  // L2-banded bijective mapping: xcd = bid&7 owns 16 m-tiles (= batch xcd)
  const int bid = blockIdx.x;
  const int xcd = bid & 7;
  const int i = bid >> 3;             // 0..1023
  const int m0 = (xcd * 16 + (i & 15)) * 128;
  const int n0 = (i >> 4) * 128;

  // staging: thread covers row (chunk*8 + lane>>3), phys 16B-chunk lane&7,
  // global logical chunk = (lane&7) ^ (lane>>3)  (pre-swizzled source)
  const int cx = (((lane & 7) ^ (lane >> 3)) << 3);
  const unsigned short* aStage = xb + (size_t)(m0 + (lane >> 3)) * Hdim + cx;
  const unsigned short* bStage = wt + (size_t)(n0 + (lane >> 3)) * Hdim + cx;

  // fragment reads: row&7 == lane&7; phys chunk = logical ^ (row&7)
  const int aOff = (wr * 64 + la15) * 128;
  const int bOff = (wc * 64 + la15) * 128;
  const int swz0 = (((lane >> 4) ^ (lane & 7)) << 4);
  const int swz1 = (((4 + (lane >> 4)) ^ (lane & 7)) << 4);

  f32x4 acc[4][4];
#pragma unroll
  for (int ii = 0; ii < 4; ++ii)
#pragma unroll
    for (int jj = 0; jj < 4; ++jj) acc[ii][jj] = (f32x4){0.f, 0.f, 0.f, 0.f};

  for (int k0 = 0; k0 < Hdim; k0 += 64) {
    __syncthreads();   // all reads of previous tile done
#pragma unroll
    for (int p = 0; p < 4; ++p) {
      const int c = p * 4 + wave;
      gload16(aStage + (size_t)c * 8 * Hdim + k0, smem + c * 1024);
    }
#pragma unroll
    for (int p = 0; p < 4; ++p) {
      const int c = p * 4 + wave;
      gload16(bStage + (size_t)c * 8 * Hdim + k0, smem + 16384 + c * 1024);
    }
    __syncthreads();   // compiler drains vmcnt before barrier -> LDS ready
    {
      bf16x8 af[4], bf[4];
#pragma unroll
      for (int ii = 0; ii < 4; ++ii)
        af[ii] = *(const bf16x8*)(smem + aOff + ii * 2048 + swz0);
#pragma unroll
      for (int jj = 0; jj < 4; ++jj)
        bf[jj] = *(const bf16x8*)(smem + 16384 + bOff + jj * 2048 + swz0);
#pragma unroll
      for (int ii = 0; ii < 4; ++ii)
#pragma unroll
        for (int jj = 0; jj < 4; ++jj)
          acc[ii][jj] = __builtin_amdgcn_mfma_f32_16x16x32_bf16(af[ii], bf[jj], acc[ii][jj], 0, 0, 0);
#pragma unroll
      for (int ii = 0; ii < 4; ++ii)
        af[ii] = *(const bf16x8*)(smem + aOff + ii * 2048 + swz1);
#pragma unroll
      for (int jj = 0; jj < 4; ++jj)
        bf[jj] = *(const bf16x8*)(smem + 16384 + bOff + jj * 2048 + swz1);
#pragma unroll
      for (int ii = 0; ii < 4; ++ii)
#pragma unroll
        for (int jj = 0; jj < 4; ++jj)
          acc[ii][jj] = __builtin_amdgcn_mfma_f32_16x16x32_bf16(af[ii], bf[jj], acc[ii][jj], 0, 0, 0);
    }
  }
  __syncthreads();   // all LDS reads done -> safe to reuse as out staging

  // ---------------- epilogue: bias + relu + routing weight + e-reduce ----------------
  // C frag: row = i*16 + (lane>>4)*4 + r (+wr*64), col = j*16 + la15 (+wc*64)
  float* outb = (float*)smem;                 // [128][17] padded f32
  const int bidx = m0 >> 11;                  // == xcd
  const float rw = routing[bidx * Edim + (lane & 7)];
  const bool writer = ((lane & 7) == 0);
#pragma unroll
  for (int j = 0; j < 4; ++j) {
    const int dloc = wc * 8 + j * 2 + ((lane >> 3) & 1);
    const float bias = be[(lane & 7) * Hdim + (n0 >> 3) + dloc];
#pragma unroll
    for (int ii = 0; ii < 4; ++ii) {
#pragma unroll
      for (int r = 0; r < 4; ++r) {
        float v = fmaxf(acc[ii][j][r] + bias, 0.f) * rw;
        v += __shfl_xor(v, 1, 64);
        v += __shfl_xor(v, 2, 64);
        v += __shfl_xor(v, 4, 64);
        if (writer) {
          const int row = wr * 64 + ii * 16 + ((lane >> 4) << 2) + r;
          outb[row * 17 + dloc] = v;
        }
      }
    }
  }
  __syncthreads();
  // coalesced store of the block's 128 x 16 f32 out-tile
  const size_t obase = (size_t)m0 * Hdim + (n0 >> 3);
#pragma unroll
  for (int it = 0; it < 2; ++it) {
    const int idx = it * 256 + t;
    const int r = idx >> 2;
    const int c = (idx & 3) << 2;
    float4 vv;
    vv.x = outb[r * 17 + c];
    vv.y = outb[r * 17 + c + 1];
    vv.z = outb[r * 17 + c + 2];
    vv.w = outb[r * 17 + c + 3];
    *(float4*)(out + obase + (size_t)r * Hdim + c) = vv;
  }
}

extern "C" void kernel_launch(void* const* d_in, const int* in_sizes, int n_in,
                              void* d_out, int out_size, void* d_ws, size_t ws_size,
                              hipStream_t stream) {
  const float* x   = (const float*)d_in[0];
  const float* We  = (const float*)d_in[1];
  const float* be  = (const float*)d_in[2];
  const float* Wr1 = (const float*)d_in[3];
  const float* br1 = (const float*)d_in[4];
  const float* Wr2 = (const float*)d_in[5];
  const float* br2 = (const float*)d_in[6];
  float* out = (float*)d_out;

  char* ws = (char*)d_ws;
  unsigned short* xb = (unsigned short*)ws;                  // 33,554,432 B
  unsigned short* wt = (unsigned short*)(ws + 33554432);     // 16,777,216 B
  float* part    = (float*)(ws + 50331648);                  //  4,194,304 B
  float* xm      = (float*)(ws + 54525952);                  //     32,768 B
  float* hbuf    = (float*)(ws + 54558720);                  //     32,768 B
  float* routing = (float*)(ws + 54591488);                  //        256 B

  k_prep<<<dim3(2560), 256, 0, stream>>>(x, xb, part, We, wt);
  k_mean<<<dim3(16, Bdim), 256, 0, stream>>>(part, xm);
  k_r1<<<dim3(8, Bdim), 256, 0, stream>>>(xm, Wr1, br1, hbuf);
  k_router2<<<1, 64, 0, stream>>>(hbuf, Wr2, br2, routing);
  k_moe_gemm<<<dim3(8192), 256, 0, stream>>>(xb, wt, be, routing, out);
}